// Round 1
// baseline (54.453 us; speedup 1.0000x reference)
//
#include <hip/hip_runtime.h>

typedef __attribute__((ext_vector_type(8))) short short8;
typedef __attribute__((ext_vector_type(4))) float f32x4;
typedef unsigned int uint32;
typedef unsigned short ushort_t;

// LDS layout (bytes). All bf16, row-major, XOR-swizzled.
#define LDS_FB   0u        // Fb  [128][64]  stride 128B
#define LDS_FBT  16384u    // FbT [64][128]  stride 256B
#define LDS_GB   32768u    // Gb  [64][64]   stride 128B
#define LDS_HTB  40960u    // HTb [64][64]   stride 128B
#define LDS_KB   49152u    // Kb  [64][64]   stride 128B (= K_w row-major)
#define LDS_QB   57344u    // Qb  [64][64]   stride 128B (= Q_w row-major)

__device__ __forceinline__ uint32 swz(uint32 base, uint32 row, uint32 colByte, uint32 stride) {
    return (base + row * stride + colByte) ^ ((row & 7u) << 4);
}
__device__ __forceinline__ ushort_t f2bf(float x) {  // RNE f32 -> bf16 bits
    uint32 u = __float_as_uint(x);
    return (ushort_t)((u + 0x7FFFu + ((u >> 16) & 1u)) >> 16);
}
__device__ __forceinline__ float bf2f(ushort_t b) {
    return __uint_as_float(((uint32)b) << 16);
}

__global__ __launch_bounds__(256, 2)
void sam3e_kernel(const float* __restrict__ F,
                  const float* __restrict__ Kw,
                  const float* __restrict__ Qw,
                  float* __restrict__ out) {
    __shared__ __align__(128) unsigned char smem[65536];
    const int t    = threadIdx.x;
    const int lane = t & 63;
    const int wave = t >> 6;          // 0..3
    const int b    = blockIdx.x;
    const int r16  = lane & 15;       // fragment row/col-in-tile
    const int kq   = lane >> 4;       // quarter-wave 0..3

    // ---- stage K_w, Q_w -> bf16 LDS (swizzled). 4096 floats each.
    #pragma unroll
    for (int i = 0; i < 16; ++i) {
        int idx = t + 256 * i;
        int r = idx >> 6, c = idx & 63;
        *(ushort_t*)(smem + swz(LDS_KB, r, 2u * c, 128u)) = f2bf(Kw[idx]);
        *(ushort_t*)(smem + swz(LDS_QB, r, 2u * c, 128u)) = f2bf(Qw[idx]);
    }

    // ---- stage F (batch b): Fb row-major + FbT transposed
    const float* Fg = F + (size_t)b * 8192;
    {
        int n0 = t >> 4;              // 0..15
        int c4 = (t & 15) * 4;        // float column
        #pragma unroll
        for (int i = 0; i < 8; ++i) {
            int n = n0 + 16 * i;
            float4 v = *(const float4*)(Fg + n * 64 + c4);
            ushort_t b0 = f2bf(v.x), b1 = f2bf(v.y), b2 = f2bf(v.z), b3 = f2bf(v.w);
            uint2 pk;
            pk.x = (uint32)b0 | ((uint32)b1 << 16);
            pk.y = (uint32)b2 | ((uint32)b3 << 16);
            *(uint2*)(smem + swz(LDS_FB, n, 2u * c4, 128u)) = pk;
            *(ushort_t*)(smem + swz(LDS_FBT, c4 + 0, 2u * n, 256u)) = b0;
            *(ushort_t*)(smem + swz(LDS_FBT, c4 + 1, 2u * n, 256u)) = b1;
            *(ushort_t*)(smem + swz(LDS_FBT, c4 + 2, 2u * n, 256u)) = b2;
            *(ushort_t*)(smem + swz(LDS_FBT, c4 + 3, 2u * n, 256u)) = b3;
        }
    }
    __syncthreads();

    // ---- G = F^T F  (64x64, K=128). Wave w owns row band 16w..16w+15.
    f32x4 accG[4];
    #pragma unroll
    for (int i = 0; i < 4; ++i) accG[i] = (f32x4){0.f, 0.f, 0.f, 0.f};
    #pragma unroll
    for (int kk = 0; kk < 4; ++kk) {
        uint32 kb = (uint32)(32 * kk + 8 * kq) * 2u;
        short8 a = *(const short8*)(smem + swz(LDS_FBT, 16 * wave + r16, kb, 256u));
        #pragma unroll
        for (int tn = 0; tn < 4; ++tn) {
            short8 bb = *(const short8*)(smem + swz(LDS_FBT, 16 * tn + r16, kb, 256u));
            accG[tn] = __builtin_amdgcn_mfma_f32_16x16x32_bf16(a, bb, accG[tn], 0, 0, 0);
        }
    }
    #pragma unroll
    for (int tn = 0; tn < 4; ++tn)
        #pragma unroll
        for (int r = 0; r < 4; ++r)
            *(ushort_t*)(smem + swz(LDS_GB, 16 * wave + 4 * kq + r, 2u * (16 * tn + r16), 128u))
                = f2bf(accG[tn][r]);
    __syncthreads();

    // ---- HT = G @ K_w^T  (64x64, K=64). HT[e][d] = H[d][e], H = K_w G.
    f32x4 accH[4];
    #pragma unroll
    for (int i = 0; i < 4; ++i) accH[i] = (f32x4){0.f, 0.f, 0.f, 0.f};
    #pragma unroll
    for (int kk = 0; kk < 2; ++kk) {
        uint32 kb = (uint32)(32 * kk + 8 * kq) * 2u;
        short8 a = *(const short8*)(smem + swz(LDS_GB, 16 * wave + r16, kb, 128u));
        #pragma unroll
        for (int tn = 0; tn < 4; ++tn) {
            short8 bb = *(const short8*)(smem + swz(LDS_KB, 16 * tn + r16, kb, 128u));
            accH[tn] = __builtin_amdgcn_mfma_f32_16x16x32_bf16(a, bb, accH[tn], 0, 0, 0);
        }
    }
    #pragma unroll
    for (int tn = 0; tn < 4; ++tn)
        #pragma unroll
        for (int r = 0; r < 4; ++r)
            *(ushort_t*)(smem + swz(LDS_HTB, 16 * wave + 4 * kq + r, 2u * (16 * tn + r16), 128u))
                = f2bf(accH[tn][r]);
    __syncthreads();

    // ---- T = F @ H, QF = F @ Q_w^T  (128x64 each, K=64).
    // Wave w owns row bands 2w, 2w+1 (16 rows each) x all 4 col tiles.
    f32x4 accT[2][4], accQ[2][4];
    #pragma unroll
    for (int i = 0; i < 2; ++i)
        #pragma unroll
        for (int j = 0; j < 4; ++j) {
            accT[i][j] = (f32x4){0.f, 0.f, 0.f, 0.f};
            accQ[i][j] = (f32x4){0.f, 0.f, 0.f, 0.f};
        }
    #pragma unroll
    for (int kk = 0; kk < 2; ++kk) {
        uint32 kb = (uint32)(32 * kk + 8 * kq) * 2u;
        short8 a0 = *(const short8*)(smem + swz(LDS_FB, 16 * (2 * wave + 0) + r16, kb, 128u));
        short8 a1 = *(const short8*)(smem + swz(LDS_FB, 16 * (2 * wave + 1) + r16, kb, 128u));
        #pragma unroll
        for (int tn = 0; tn < 4; ++tn) {
            short8 bt = *(const short8*)(smem + swz(LDS_HTB, 16 * tn + r16, kb, 128u));
            short8 bq = *(const short8*)(smem + swz(LDS_QB, 16 * tn + r16, kb, 128u));
            accT[0][tn] = __builtin_amdgcn_mfma_f32_16x16x32_bf16(a0, bt, accT[0][tn], 0, 0, 0);
            accQ[0][tn] = __builtin_amdgcn_mfma_f32_16x16x32_bf16(a0, bq, accQ[0][tn], 0, 0, 0);
            accT[1][tn] = __builtin_amdgcn_mfma_f32_16x16x32_bf16(a1, bt, accT[1][tn], 0, 0, 0);
            accQ[1][tn] = __builtin_amdgcn_mfma_f32_16x16x32_bf16(a1, bq, accQ[1][tn], 0, 0, 0);
        }
    }

    // ---- epilogue: out = F .* T + QF
    float* og = out + (size_t)b * 8192;
    #pragma unroll
    for (int i2 = 0; i2 < 2; ++i2) {
        #pragma unroll
        for (int tn = 0; tn < 4; ++tn) {
            #pragma unroll
            for (int r = 0; r < 4; ++r) {
                int n = 16 * (2 * wave + i2) + 4 * kq + r;
                int d = 16 * tn + r16;
                float f = bf2f(*(const ushort_t*)(smem + swz(LDS_FB, n, 2u * d, 128u)));
                og[n * 64 + d] = fmaf(f, accT[i2][tn][r], accQ[i2][tn][r]);
            }
        }
    }
}

extern "C" void kernel_launch(void* const* d_in, const int* in_sizes, int n_in,
                              void* d_out, int out_size, void* d_ws, size_t ws_size,
                              hipStream_t stream) {
    const float* F  = (const float*)d_in[0];
    const float* Kw = (const float*)d_in[1];
    const float* Qw = (const float*)d_in[2];
    float* out = (float*)d_out;
    int Bt = in_sizes[0] / (128 * 64);   // 4096
    sam3e_kernel<<<dim3(Bt), dim3(256), 0, stream>>>(F, Kw, Qw, out);
}